// Round 1
// baseline (299.959 us; speedup 1.0000x reference)
//
#include <hip/hip_runtime.h>

// 8-level sym8 wavelet packet transform, B=128 rows of L0=65536, f32.
// Per level: reflect-pad (padl=14, padr=14+(L%2)), stride-2 16-tap
// cross-correlation with flipped dec filters, rows interleaved (lo,hi).
// Level lengths: 65536->32775->16395->8205->4110->2062->1038->526->270.
// Final level fuses log(x^2 + 1e-12).

#define PADL 14

// fl[t] = dec_lo[15-t]  (flipped low-pass, cross-correlation form)
__device__ __constant__ float FL[16] = {
     0.0018899503327594609f, -0.0003029205147213668f, -0.01495225833704823f,
     0.003808752013890615f,   0.049137179673607506f,  -0.027219029917056003f,
    -0.05194583810770904f,    0.3644418948353314f,     0.7771857517005235f,
     0.4813596512583722f,    -0.061273359067658524f,  -0.1432942383508097f,
     0.007607487324917605f,   0.03169508781149298f,   -0.0005421323317911481f,
    -0.0033824159510061256f
};

// fh[t] = dec_hi[15-t] = (t odd ? +1 : -1) * dec_lo[t]
__device__ __constant__ float FH[16] = {
     0.0033824159510061256f, -0.0005421323317911481f, -0.03169508781149298f,
     0.007607487324917605f,   0.1432942383508097f,    -0.061273359067658524f,
    -0.4813596512583722f,     0.7771857517005235f,    -0.3644418948353314f,
    -0.05194583810770904f,    0.027219029917056003f,   0.049137179673607506f,
    -0.003808752013890615f,  -0.01495225833704823f,    0.0003029205147213668f,
     0.0018899503327594609f
};

template <bool FUSE_LOG>
__global__ void dwt_level(const float* __restrict__ x, float* __restrict__ y,
                          int Lin, int Lout) {
    const int j = blockIdx.x * blockDim.x + threadIdx.x;
    const int n = blockIdx.y;
    if (j >= Lout) return;

    const float* row = x + (size_t)n * (size_t)Lin;
    float lo = 0.0f, hi = 0.0f;
    const int p0 = 2 * j - PADL;

#pragma unroll
    for (int t = 0; t < 16; ++t) {
        int q = p0 + t;
        q = (q < 0) ? -q : q;                       // left reflect (no edge repeat)
        q = (q >= Lin) ? (2 * Lin - 2 - q) : q;     // right reflect
        const float v = row[q];
        lo = fmaf(v, FL[t], lo);
        hi = fmaf(v, FH[t], hi);
    }

    const size_t o0 = (size_t)(2 * n) * (size_t)Lout + (size_t)j;
    const size_t o1 = o0 + (size_t)Lout;
    if (FUSE_LOG) {
        y[o0] = logf(fmaf(lo, lo, 1e-12f));
        y[o1] = logf(fmaf(hi, hi, 1e-12f));
    } else {
        y[o0] = lo;
        y[o1] = hi;
    }
}

extern "C" void kernel_launch(void* const* d_in, const int* in_sizes, int n_in,
                              void* d_out, int out_size, void* d_ws, size_t ws_size,
                              hipStream_t stream) {
    const int L0 = 65536;
    const int B = in_sizes[0] / L0;

    const float* src = (const float*)d_in[0];
    float* ws  = (float*)d_ws;   // even-level outputs (max 8,617,984 floats ~34.5 MB)
    float* out = (float*)d_out;  // odd-level scratch + final output

    int N = B;        // rows at current level input
    int Lin = L0;

    for (int lev = 0; lev < 8; ++lev) {
        const int Lout = (Lin + 1) / 2 + 7;
        float* dst = (lev == 7) ? out : ((lev & 1) ? out : ws);

        dim3 block(256);
        dim3 grid((Lout + 255) / 256, N);
        if (lev == 7) {
            dwt_level<true><<<grid, block, 0, stream>>>(src, dst, Lin, Lout);
        } else {
            dwt_level<false><<<grid, block, 0, stream>>>(src, dst, Lin, Lout);
        }

        src = dst;
        N *= 2;
        Lin = Lout;
    }
}

// Round 2
// 222.905 us; speedup vs baseline: 1.3457x; 1.3457x over previous
//
#include <hip/hip_runtime.h>

// 8-level sym8 wavelet packet transform, B=128 rows of L0=65536, f32.
// Register-blocked: each thread computes NO=8 consecutive output positions
// (both lo and hi), loading its 30-float input window once.
// Level lengths: 65536->32775->16395->8205->4110->2062->1038->526->270.
// Final level fuses log(x^2 + 1e-12).

#define PADL 14
#define NO 8
#define WIN (2 * NO + 14)   // 30-float input window per thread

// fl[t] = dec_lo[15-t]  (flipped low-pass, cross-correlation form)
__device__ __constant__ float FL[16] = {
     0.0018899503327594609f, -0.0003029205147213668f, -0.01495225833704823f,
     0.003808752013890615f,   0.049137179673607506f,  -0.027219029917056003f,
    -0.05194583810770904f,    0.3644418948353314f,     0.7771857517005235f,
     0.4813596512583722f,    -0.061273359067658524f,  -0.1432942383508097f,
     0.007607487324917605f,   0.03169508781149298f,   -0.0005421323317911481f,
    -0.0033824159510061256f
};

// fh[t] = dec_hi[15-t] = (t odd ? +1 : -1) * dec_lo[t]
__device__ __constant__ float FH[16] = {
     0.0033824159510061256f, -0.0005421323317911481f, -0.03169508781149298f,
     0.007607487324917605f,   0.1432942383508097f,    -0.061273359067658524f,
    -0.4813596512583722f,     0.7771857517005235f,    -0.3644418948353314f,
    -0.05194583810770904f,    0.027219029917056003f,   0.049137179673607506f,
    -0.003808752013890615f,  -0.01495225833704823f,    0.0003029205147213668f,
     0.0018899503327594609f
};

template <bool FUSE_LOG>
__global__ __launch_bounds__(256) void dwt_level_rb(
    const float* __restrict__ x, float* __restrict__ y,
    int Lin, int Lout, int N, int gpr) {
    const int tid = blockIdx.x * blockDim.x + threadIdx.x;
    const unsigned n = (unsigned)tid / (unsigned)gpr;
    if (n >= (unsigned)N) return;
    const int g = tid - (int)n * gpr;
    const int j0 = g * NO;
    const int p0 = 2 * j0 - PADL;
    const float* row = x + (size_t)n * (size_t)Lin;

    float w[WIN];
    if (p0 >= 0 && p0 + WIN <= Lin) {
        // interior: straight-line loads, 30 independent -> deep ILP
#pragma unroll
        for (int t = 0; t < WIN; ++t) w[t] = row[p0 + t];
    } else {
        // edge: analytic reflect (single reflection suffices, L >= 270 > 30)
#pragma unroll
        for (int t = 0; t < WIN; ++t) {
            int q = p0 + t;
            q = (q < 0) ? -q : q;
            q = (q >= Lin) ? (2 * Lin - 2 - q) : q;
            w[t] = row[q];
        }
    }

    float lo[NO], hi[NO];
#pragma unroll
    for (int i = 0; i < NO; ++i) { lo[i] = 0.0f; hi[i] = 0.0f; }
#pragma unroll
    for (int t = 0; t < 16; ++t) {
        const float cl = FL[t];
        const float ch = FH[t];
#pragma unroll
        for (int i = 0; i < NO; ++i) {
            const float v = w[2 * i + t];
            lo[i] = fmaf(v, cl, lo[i]);
            hi[i] = fmaf(v, ch, hi[i]);
        }
    }

    float* y0 = y + (size_t)(2 * n) * (size_t)Lout + (size_t)j0;
    float* y1 = y0 + Lout;
#pragma unroll
    for (int i = 0; i < NO; ++i) {
        if (j0 + i < Lout) {
            if (FUSE_LOG) {
                y0[i] = logf(fmaf(lo[i], lo[i], 1e-12f));
                y1[i] = logf(fmaf(hi[i], hi[i], 1e-12f));
            } else {
                y0[i] = lo[i];
                y1[i] = hi[i];
            }
        }
    }
}

extern "C" void kernel_launch(void* const* d_in, const int* in_sizes, int n_in,
                              void* d_out, int out_size, void* d_ws, size_t ws_size,
                              hipStream_t stream) {
    const int L0 = 65536;
    const int B = in_sizes[0] / L0;

    const float* src = (const float*)d_in[0];
    float* ws  = (float*)d_ws;   // even-level outputs (max ~34.5 MB)
    float* out = (float*)d_out;  // odd-level scratch + final output

    int N = B;
    int Lin = L0;

    for (int lev = 0; lev < 8; ++lev) {
        const int Lout = (Lin + 1) / 2 + 7;
        float* dst = (lev == 7) ? out : ((lev & 1) ? out : ws);

        const int gpr = (Lout + NO - 1) / NO;       // output groups per row
        const long long T = (long long)N * gpr;     // total threads
        const int grid = (int)((T + 255) / 256);

        if (lev == 7) {
            dwt_level_rb<true><<<grid, 256, 0, stream>>>(src, dst, Lin, Lout, N, gpr);
        } else {
            dwt_level_rb<false><<<grid, 256, 0, stream>>>(src, dst, Lin, Lout, N, gpr);
        }

        src = dst;
        N *= 2;
        Lin = Lout;
    }
}